// Round 6
// baseline (181.565 us; speedup 1.0000x reference)
//
#include <hip/hip_runtime.h>
#include <stdint.h>

#define B_ 2
#define S_ 2048
#define D_ 512
#define H_ 8
#define WIN_ 16
#define DIL_ 2
#define G_ 64
#define L_ (S_ - G_)   // 1984;  B_*L_ = 3968 = 31*128 exactly

typedef short bf16x8 __attribute__((ext_vector_type(8)));
typedef float f32x4 __attribute__((ext_vector_type(4)));
typedef unsigned short u16;

__device__ __forceinline__ float bf2f(u16 h) {
  return __uint_as_float(((uint32_t)h) << 16);
}
__device__ __forceinline__ u16 f2bf(float f) {
  uint32_t u = __float_as_uint(f);
  uint32_t r = (u + 0x7fffu + ((u >> 16) & 1u)) >> 16;
  return (u16)r;
}

__device__ __forceinline__ void gload16(const u16* g, u16* l) {
  __builtin_amdgcn_global_load_lds(
      (const __attribute__((address_space(1))) void*)g,
      (__attribute__((address_space(3))) void*)l, 16, 0, 0);
}

// ---------------- convert fp32 -> bf16 ----------------
struct CvtJob { const float* src; u16* dst; int n4; };
struct CvtArgs { CvtJob job[9]; };

__global__ __launch_bounds__(256) void cvt_kernel(CvtArgs a) {
  CvtJob j = a.job[blockIdx.y];
  int stride = gridDim.x * blockDim.x;
  for (int i = blockIdx.x * blockDim.x + threadIdx.x; i < j.n4; i += stride) {
    float4 v = reinterpret_cast<const float4*>(j.src)[i];
    ushort4 o;
    o.x = f2bf(v.x); o.y = f2bf(v.y); o.z = f2bf(v.z); o.w = f2bf(v.w);
    reinterpret_cast<ushort4*>(j.dst)[i] = o;
  }
}

// ---------------- unified bf16 MFMA GEMM: Y = X @ W^T + bias ----------------
// m97-class: BM=128 x BN=128, BK=32, 4 waves (2x2), acc 4x4 per wave.
// 2-phase single-barrier pipeline: STAGE(next buf) -> compute(cur) -> barrier.
struct Job {
  const u16* X; const u16* W; const float* bias; void* Y;
  int rpb;     // rows per batch (M = 2*rpb)
  int xoff;    // X row offset within batch
  long xbs;    // X batch stride (elems)
  int yoff;    // Y row offset within batch
  long ybs;    // Y batch stride (elems)
  int out_f32;
};
struct GemmLaunch { int start[6]; Job job[6]; };

__global__ __launch_bounds__(256) void gemm_kernel(GemmLaunch a) {
  // XCD-bijective swizzle (host guarantees gridDim.x % 8 == 0)
  int bid = (int)blockIdx.x;
  bid = (bid & 7) * ((int)gridDim.x >> 3) + (bid >> 3);

  int j = 0;
#pragma unroll
  for (int i = 1; i < 6; ++i) j = (bid >= a.start[i]) ? i : j;
  const Job jb = a.job[j];
  bid -= a.start[j];
  const int tm = bid >> 2, tn = bid & 3;   // ntiles_n = 512/128 = 4
  const int row0 = tm * 128, n0 = tn * 128;

  __shared__ __align__(16) u16 As[2][128 * 32];  // 2 x 8 KB
  __shared__ __align__(16) u16 Bs[2][128 * 32];  // 2 x 8 KB

  const int tid = threadIdx.x, lane = tid & 63, w = tid >> 6;
  const int wm = w >> 1, wn = w & 1;

  // staging: thread covers A rows {row0 + tid/4, row0+64+tid/4}, same for B,
  // k-chunk (tid&3)*8.  Wave w's 64 lanes fill 16 rows = 1 KB contiguous LDS.
  const int rA = tid >> 2;          // 0..63
  const int kq = (tid & 3) * 8;

  const int r0 = row0 + rA,      b0 = r0 >= jb.rpb;
  const int r1 = row0 + 64 + rA, b1 = r1 >= jb.rpb;
  const u16* xa0 = jb.X + (size_t)(b0 ? jb.xbs : 0) +
                   (size_t)(jb.xoff + r0 - (b0 ? jb.rpb : 0)) * 512 + kq;
  const u16* xa1 = jb.X + (size_t)(b1 ? jb.xbs : 0) +
                   (size_t)(jb.xoff + r1 - (b1 ? jb.rpb : 0)) * 512 + kq;
  const u16* wb0 = jb.W + (size_t)(n0 + rA) * 512 + kq;
  const u16* wb1 = jb.W + (size_t)(n0 + 64 + rA) * 512 + kq;

  f32x4 acc[4][4];
#pragma unroll
  for (int i = 0; i < 4; ++i)
#pragma unroll
    for (int k = 0; k < 4; ++k) acc[i][k] = (f32x4){0.f, 0.f, 0.f, 0.f};

  auto stage = [&](int buf, int kof) {
    gload16(xa0 + kof, &As[buf][w * 512]);
    gload16(xa1 + kof, &As[buf][2048 + w * 512]);
    gload16(wb0 + kof, &Bs[buf][w * 512]);
    gload16(wb1 + kof, &Bs[buf][2048 + w * 512]);
  };
  auto compute = [&](int buf) {
    bf16x8 af[4], bfv[4];
#pragma unroll
    for (int fm = 0; fm < 4; ++fm)
      af[fm] = *(const bf16x8*)&As[buf][(wm * 64 + fm * 16 + (lane & 15)) * 32 + 8 * (lane >> 4)];
#pragma unroll
    for (int fn = 0; fn < 4; ++fn)
      bfv[fn] = *(const bf16x8*)&Bs[buf][(wn * 64 + fn * 16 + (lane & 15)) * 32 + 8 * (lane >> 4)];
#pragma unroll
    for (int fm = 0; fm < 4; ++fm)
#pragma unroll
      for (int fn = 0; fn < 4; ++fn)
        acc[fm][fn] = __builtin_amdgcn_mfma_f32_16x16x32_bf16(af[fm], bfv[fn], acc[fm][fn], 0, 0, 0);
  };

  stage(0, 0);
  __syncthreads();                  // compiler emits vmcnt(0) drain + barrier
  int cur = 0;
  for (int kt = 0; kt < 15; ++kt) {
    stage(cur ^ 1, (kt + 1) * 32);  // next tile's loads fly during compute
    compute(cur);
    __syncthreads();
    cur ^= 1;
  }
  compute(cur);

#pragma unroll
  for (int fm = 0; fm < 4; ++fm) {
#pragma unroll
    for (int fn = 0; fn < 4; ++fn) {
#pragma unroll
      for (int r = 0; r < 4; ++r) {
        const int row = row0 + wm * 64 + fm * 16 + (lane >> 4) * 4 + r;
        const int col = n0 + wn * 64 + fn * 16 + (lane & 15);
        const int b = row >= jb.rpb;
        const int rr = row - (b ? jb.rpb : 0);
        const size_t yi = (size_t)(b ? jb.ybs : 0) + (size_t)(jb.yoff + rr) * 512 + col;
        const float v = acc[fm][fn][r] + jb.bias[col];
        if (jb.out_f32) ((float*)jb.Y)[yi] = v;
        else            ((u16*)jb.Y)[yi]   = f2bf(v);
      }
    }
  }
}

// ---------------- fused attention (local windowed + global) ----------------
// wave per (b,l) for local: lane owns 8 contiguous elems of the 512-row
// (head = lane>>3); per-head dot via 3-level shfl_xor within 8-lane groups.
// Local blocks XCD-swizzled so each XCD owns a contiguous l-range (L2-resident
// K/V window ~0.5 MB/XCD).
__global__ __launch_bounds__(256) void attn_kernel(const u16* qp, const u16* kp,
                                                   const u16* vp, u16* ob,
                                                   const u16* qgp, const u16* kgp,
                                                   const u16* vgp, u16* ogp) {
  const int lane = threadIdx.x & 63;
  int bid = (int)blockIdx.x;
  const int nbl = (B_ * L_) / 4;    // 992 = 8*124
  if (bid < nbl) bid = (bid & 7) * (nbl >> 3) + (bid >> 3);
  const int wid = bid * 4 + (threadIdx.x >> 6);

  if (wid < B_ * L_) {
    const int l = wid % L_;
    const int brow = wid - l;   // batch base row
    float q[8];
    {
      bf16x8 qv = *(const bf16x8*)&qp[(size_t)wid * 512 + lane * 8];
#pragma unroll
      for (int e = 0; e < 8; ++e) q[e] = bf2f((u16)qv[e]);
    }
    float s[WIN_];
#pragma unroll
    for (int w2 = 0; w2 < WIN_; ++w2) {
      int ki = l + DIL_ * w2 - WIN_;
      ki = ki < 0 ? 0 : (ki > L_ - 1 ? L_ - 1 : ki);
      bf16x8 kv = *(const bf16x8*)&kp[(size_t)(brow + ki) * 512 + lane * 8];
      float p = 0.f;
#pragma unroll
      for (int e = 0; e < 8; ++e) p = fmaf(q[e], bf2f((u16)kv[e]), p);
      p += __shfl_xor(p, 1); p += __shfl_xor(p, 2); p += __shfl_xor(p, 4);
      s[w2] = p * 0.125f;
    }
    float m = s[0];
#pragma unroll
    for (int w2 = 1; w2 < WIN_; ++w2) m = fmaxf(m, s[w2]);
    float sum = 0.f;
#pragma unroll
    for (int w2 = 0; w2 < WIN_; ++w2) { s[w2] = __expf(s[w2] - m); sum += s[w2]; }
    const float inv = 1.0f / sum;
    float acc[8] = {0.f};
#pragma unroll
    for (int w2 = 0; w2 < WIN_; ++w2) {
      int ki = l + DIL_ * w2 - WIN_;
      ki = ki < 0 ? 0 : (ki > L_ - 1 ? L_ - 1 : ki);
      bf16x8 vv = *(const bf16x8*)&vp[(size_t)(brow + ki) * 512 + lane * 8];
#pragma unroll
      for (int e = 0; e < 8; ++e) acc[e] = fmaf(s[w2], bf2f((u16)vv[e]), acc[e]);
    }
    bf16x8 o8;
#pragma unroll
    for (int e = 0; e < 8; ++e) o8[e] = (short)f2bf(acc[e] * inv);
    *(bf16x8*)&ob[(size_t)wid * 512 + lane * 8] = o8;
  } else {
    const int g = wid - B_ * L_;         // 0..127
    const int base = (g >> 6) * 64;      // b*64
    const int qi = g & 63;
    float q[8];
    {
      bf16x8 qv = *(const bf16x8*)&qgp[(size_t)(base + qi) * 512 + lane * 8];
#pragma unroll
      for (int e = 0; e < 8; ++e) q[e] = bf2f((u16)qv[e]);
    }
    float m = -1e30f, sum = 0.f, acc[8] = {0.f};
    for (int j2 = 0; j2 < 64; ++j2) {
      bf16x8 kv = *(const bf16x8*)&kgp[(size_t)(base + j2) * 512 + lane * 8];
      float p = 0.f;
#pragma unroll
      for (int e = 0; e < 8; ++e) p = fmaf(q[e], bf2f((u16)kv[e]), p);
      p += __shfl_xor(p, 1); p += __shfl_xor(p, 2); p += __shfl_xor(p, 4);
      p *= 0.125f;
      const float mn = fmaxf(m, p);
      const float c  = __expf(m - mn);
      const float pe = __expf(p - mn);
      sum = sum * c + pe;
      m = mn;
      bf16x8 vv = *(const bf16x8*)&vgp[(size_t)(base + j2) * 512 + lane * 8];
#pragma unroll
      for (int e = 0; e < 8; ++e) acc[e] = acc[e] * c + pe * bf2f((u16)vv[e]);
    }
    const float inv = 1.0f / sum;
    bf16x8 o8;
#pragma unroll
    for (int e = 0; e < 8; ++e) o8[e] = (short)f2bf(acc[e] * inv);
    *(bf16x8*)&ogp[(size_t)(base + qi) * 512 + lane * 8] = o8;
  }
}

// ---------------- host ----------------
extern "C" void kernel_launch(void* const* d_in, const int* in_sizes, int n_in,
                              void* d_out, int out_size, void* d_ws, size_t ws_size,
                              hipStream_t stream) {
  const float* query   = (const float*)d_in[0];
  const float* key     = (const float*)d_in[1];
  const float* value   = (const float*)d_in[2];
  const float* wq      = (const float*)d_in[3];
  const float* bq      = (const float*)d_in[4];
  const float* wk      = (const float*)d_in[5];
  const float* bk      = (const float*)d_in[6];
  const float* wv      = (const float*)d_in[7];
  const float* bv      = (const float*)d_in[8];
  const float* wo      = (const float*)d_in[9];
  const float* bo      = (const float*)d_in[10];
  const float* g_in_w  = (const float*)d_in[11];
  const float* g_in_b  = (const float*)d_in[12];
  const float* g_out_w = (const float*)d_in[13];
  const float* g_out_b = (const float*)d_in[14];
  float* out = (float*)d_out;

  u16* w16 = (u16*)d_ws;
  const size_t QKV = (size_t)B_ * S_ * D_;   // 2097152
  const size_t WSZ = (size_t)D_ * D_;        // 262144
  const size_t PSZ = (size_t)B_ * L_ * D_;   // 2031616
  const size_t GSZ = (size_t)B_ * G_ * D_;   // 65536

  u16* qb  = w16;              u16* kb  = qb + QKV;   u16* vb  = kb + QKV;
  u16* wqb = vb + QKV;         u16* wkb = wqb + WSZ;  u16* wvb = wkb + WSZ;
  u16* wob = wvb + WSZ;
  u16* gqw = wob + WSZ;        u16* gkw = gqw + WSZ;  u16* gvw = gkw + WSZ;
  u16* gow = gvw + WSZ;
  u16* qp  = gow + WSZ;        u16* kp  = qp + PSZ;   u16* vp  = kp + PSZ;
  u16* ob  = vp + PSZ;
  u16* qgp = ob + PSZ;         u16* kgp = qgp + GSZ;  u16* vgp = kgp + GSZ;
  u16* ogp = vgp + GSZ;

  // 1) convert inputs to bf16
  CvtArgs ca;
  ca.job[0] = {query, qb, (int)(QKV / 4)};
  ca.job[1] = {key,   kb, (int)(QKV / 4)};
  ca.job[2] = {value, vb, (int)(QKV / 4)};
  ca.job[3] = {wq, wqb, (int)(WSZ / 4)};
  ca.job[4] = {wk, wkb, (int)(WSZ / 4)};
  ca.job[5] = {wv, wvb, (int)(WSZ / 4)};
  ca.job[6] = {wo, wob, (int)(WSZ / 4)};
  ca.job[7] = {g_in_w, gqw, (int)(3 * WSZ / 4)};   // covers gqw,gkw,gvw
  ca.job[8] = {g_out_w, gow, (int)(WSZ / 4)};
  hipLaunchKernelGGL(cvt_kernel, dim3(512, 9), dim3(256), 0, stream, ca);

  const long XBS = (long)S_ * D_;   // 1048576
  const long PBS = (long)L_ * D_;   // 1015808
  const long GBS = (long)G_ * D_;   // 32768

  // 2) input projections: 3 local jobs (31 mtiles * 4 = 124 blocks each)
  //    + 3 global jobs (1 mtile * 4 = 4 blocks each) = 384 blocks (= 8*48)
  GemmLaunch gi;
  gi.start[0] = 0; gi.start[1] = 124; gi.start[2] = 248;
  gi.start[3] = 372; gi.start[4] = 376; gi.start[5] = 380;
  gi.job[0] = {qb, wqb, bq, qp, L_, G_, XBS, 0, PBS, 0};
  gi.job[1] = {kb, wkb, bk, kp, L_, G_, XBS, 0, PBS, 0};
  gi.job[2] = {vb, wvb, bv, vp, L_, G_, XBS, 0, PBS, 0};
  gi.job[3] = {qb, gqw, g_in_b,           qgp, G_, 0, XBS, 0, GBS, 0};
  gi.job[4] = {kb, gkw, g_in_b + D_,      kgp, G_, 0, XBS, 0, GBS, 0};
  gi.job[5] = {vb, gvw, g_in_b + 2 * D_,  vgp, G_, 0, XBS, 0, GBS, 0};
  hipLaunchKernelGGL(gemm_kernel, dim3(384), dim3(256), 0, stream, gi);

  // 3) fused attention: 992 local blocks + 32 global blocks
  hipLaunchKernelGGL(attn_kernel, dim3((B_ * L_ + 128) / 4), dim3(256), 0, stream,
                     qp, kp, vp, ob, qgp, kgp, vgp, ogp);

  // 4) output projections: local (124 blocks) + global (4) = 128 (= 8*16)
  GemmLaunch go;
  go.start[0] = 0; go.start[1] = 124;
  go.start[2] = go.start[3] = go.start[4] = go.start[5] = 0x7fffffff;
  go.job[0] = {ob,  wob, bo,      out, L_, 0, PBS, G_, XBS, 1};
  go.job[1] = {ogp, gow, g_out_b, out, G_, 0, GBS, 0,  XBS, 1};
  go.job[2] = go.job[1]; go.job[3] = go.job[1]; go.job[4] = go.job[1]; go.job[5] = go.job[1];
  hipLaunchKernelGGL(gemm_kernel, dim3(128), dim3(256), 0, stream, go);
}